// Round 1
// baseline (340.309 us; speedup 1.0000x reference)
//
#include <hip/hip_runtime.h>
#include <math.h>
#include <stdint.h>

#define Bb   128
#define Nn   100
#define Ee   3200
#define NTOT (Bb*Nn)    // 12800
#define ETOT (Bb*Ee)    // 409600

// ---------------- CSR build ----------------

__global__ __launch_bounds__(256) void k_zero(int* __restrict__ pos) {
    int i = blockIdx.x * 256 + threadIdx.x;
    if (i < NTOT) pos[i] = 0;
}

__global__ __launch_bounds__(256) void k_count(const int* __restrict__ ei, int* __restrict__ pos) {
    int ge = blockIdx.x * 256 + threadIdx.x;
    if (ge >= ETOT) return;
    int b = ge / Ee;
    int e = ge - b * Ee;
    int dst = ei[b * 2 * Ee + Ee + e] + b * Nn;
    atomicAdd(&pos[dst], 1);
}

__global__ __launch_bounds__(256) void k_scan(int* __restrict__ pos, int* __restrict__ off) {
    __shared__ int part[256];
    int t = threadIdx.x;
    const int per = NTOT / 256;  // 50
    int s = 0;
    for (int j = 0; j < per; j++) s += pos[t * per + j];
    part[t] = s;
    __syncthreads();
    for (int d = 1; d < 256; d <<= 1) {
        int v = (t >= d) ? part[t - d] : 0;
        __syncthreads();
        part[t] += v;
        __syncthreads();
    }
    int run = (t > 0) ? part[t - 1] : 0;
    for (int j = 0; j < per; j++) {
        int i = t * per + j;
        int cval = pos[i];
        off[i] = run;
        pos[i] = run;   // pos becomes the running write cursor for k_fill
        run += cval;
    }
    if (t == 255) off[NTOT] = run;
}

__global__ __launch_bounds__(256) void k_fill(const int* __restrict__ ei, int* __restrict__ pos,
                                              int* __restrict__ csrc, int* __restrict__ cge) {
    int ge = blockIdx.x * 256 + threadIdx.x;
    if (ge >= ETOT) return;
    int b = ge / Ee;
    int e = ge - b * Ee;
    int src = ei[b * 2 * Ee + e] + b * Nn;
    int dst = ei[b * 2 * Ee + Ee + e] + b * Nn;
    int idx = atomicAdd(&pos[dst], 1);
    csrc[idx] = src;
    cge[idx]  = ge;
}

// ---------------- helpers ----------------

__device__ __forceinline__ float ln16(float x, float g, float b) {
    // LayerNorm over the 16 lanes of this slot (two-pass: mean, then var)
    float s = x;
    s += __shfl_xor(s, 1, 16);
    s += __shfl_xor(s, 2, 16);
    s += __shfl_xor(s, 4, 16);
    s += __shfl_xor(s, 8, 16);
    float m = s * 0.0625f;
    float d = x - m;
    float v = d * d;
    v += __shfl_xor(v, 1, 16);
    v += __shfl_xor(v, 2, 16);
    v += __shfl_xor(v, 4, 16);
    v += __shfl_xor(v, 8, 16);
    v *= 0.0625f;
    return d * rsqrtf(v + 1e-5f) * g + b;
}

// ---------------- K4: edge MLP -> z, then q1/k1/v1 ----------------
// one wave per node; 4 edge slots x 16 channel lanes

__global__ __launch_bounds__(256) void k_zqkv(
    const float* __restrict__ nf, const float* __restrict__ ea, const float* __restrict__ ee,
    const float* __restrict__ W1, const float* __restrict__ b1,
    const float* __restrict__ W2, const float* __restrict__ b2,
    const float* __restrict__ W3, const float* __restrict__ b3,
    const float* __restrict__ lg, const float* __restrict__ lb,
    const float* __restrict__ Wq, const float* __restrict__ bq,
    const float* __restrict__ Wk, const float* __restrict__ bk,
    const float* __restrict__ Wv, const float* __restrict__ bv,
    const int* __restrict__ off, const int* __restrict__ csrc, const int* __restrict__ cge,
    float* __restrict__ z, float* __restrict__ q1, float* __restrict__ k1, float* __restrict__ v1)
{
    int lane = threadIdx.x & 63;
    int wid  = threadIdx.x >> 6;
    int n    = blockIdx.x * 4 + wid;
    int c    = lane & 15;
    int slot = lane >> 4;

    float w1r[12], w2r[16], w3r[16];
#pragma unroll
    for (int j = 0; j < 12; j++) w1r[j] = W1[c * 12 + j];
#pragma unroll
    for (int j = 0; j < 16; j++) { w2r[j] = W2[c * 16 + j]; w3r[j] = W3[c * 16 + j]; }
    float b1c = b1[c], b2c = b2[c], b3c = b3[c];
    float gC = lg[c], bC = lb[c];

    int o0 = off[n];
    int deg = off[n + 1] - o0;

    float zp = 0.f;
    for (int base = 0; base < deg; base += 4) {
        int i = base + slot;
        bool act = (i < deg);
        if (!act) i = deg - 1;          // clamp: read a real edge, discard contribution
        int src = csrc[o0 + i];
        int ge  = cge[o0 + i];
        int et  = (int)nf[src];
        float in[12];
#pragma unroll
        for (int j = 0; j < 4; j++) in[j] = ee[et * 4 + j];
#pragma unroll
        for (int j = 0; j < 8; j++) in[4 + j] = ea[(size_t)ge * 8 + j];

        float x = b1c;
#pragma unroll
        for (int j = 0; j < 12; j++) x = fmaf(w1r[j], in[j], x);
        x = fmaxf(x, 0.f);
        x = ln16(x, gC, bC);

        float y = b2c;
#pragma unroll
        for (int j = 0; j < 16; j++) y = fmaf(w2r[j], __shfl(x, j, 16), y);
        y = fmaxf(y, 0.f);
        y = ln16(y, gC, bC);

        float u = b3c;
#pragma unroll
        for (int j = 0; j < 16; j++) u = fmaf(w3r[j], __shfl(y, j, 16), u);
        u = fmaxf(u, 0.f);
        u = ln16(u, gC, bC);

        zp += act ? u : 0.f;
    }
    // sum across the 4 slots -> every lane holds z[lane&15]
    zp += __shfl_xor(zp, 16);
    zp += __shfl_xor(zp, 32);

    if (lane < 16) z[n * 16 + lane] = zp;

    // q/k/v projection: lane computes output channel `lane` of each
    float aq = bq[lane], ak = bk[lane], av = bv[lane];
#pragma unroll
    for (int j = 0; j < 16; j++) {
        float zj = __shfl(zp, j, 16);
        aq = fmaf(Wq[lane * 16 + j], zj, aq);
        ak = fmaf(Wk[lane * 16 + j], zj, ak);
        av = fmaf(Wv[lane * 16 + j], zj, av);
    }
    q1[n * 64 + lane] = aq;
    k1[n * 64 + lane] = ak;
    v1[n * 64 + lane] = av;
}

// ---------------- K5: g1 attention (one wave per node, online softmax) ----------------

__global__ __launch_bounds__(256) void k_attn1(
    const float* __restrict__ ea,
    const float* __restrict__ q1, const float* __restrict__ k1, const float* __restrict__ v1,
    const float* __restrict__ We, const float* __restrict__ Ws, const float* __restrict__ bs,
    const float* __restrict__ z,
    const int* __restrict__ off, const int* __restrict__ csrc, const int* __restrict__ cge,
    float* __restrict__ a1)
{
    int lane = threadIdx.x & 63;
    int wid  = threadIdx.x >> 6;
    int n    = blockIdx.x * 4 + wid;

    float wer[8];
#pragma unroll
    for (int j = 0; j < 8; j++) wer[j] = We[lane * 8 + j];
    float ql = q1[n * 64 + lane];

    int o0 = off[n];
    int deg = off[n + 1] - o0;

    float m = -1e30f, l = 0.f, acc = 0.f;
    for (int i = 0; i < deg; i++) {
        int src = csrc[o0 + i];
        int ge  = cge[o0 + i];
        float el = 0.f;
#pragma unroll
        for (int j = 0; j < 8; j++) el = fmaf(wer[j], ea[(size_t)ge * 8 + j], el);
        float kl = k1[src * 64 + lane];
        float t = ql * (kl + el);
        t += __shfl_xor(t, 1, 16);
        t += __shfl_xor(t, 2, 16);
        t += __shfl_xor(t, 4, 16);
        t += __shfl_xor(t, 8, 16);
        float logit = t * 0.25f;  // / sqrt(16)
        float nm = fmaxf(m, logit);
        float sc = __expf(m - nm);
        float w  = __expf(logit - nm);
        float vl = v1[src * 64 + lane];
        acc = acc * sc + w * (vl + el);
        l   = l * sc + w;
        m   = nm;
    }
    float y = (deg > 0) ? (acc / l) : 0.f;
    // mean over 4 heads
    y += __shfl_xor(y, 16);
    y += __shfl_xor(y, 32);
    y *= 0.25f;

    if (lane < 16) {
        float r = bs[lane];
#pragma unroll
        for (int j = 0; j < 16; j++) r = fmaf(Ws[lane * 16 + j], z[n * 16 + j], r);
        a1[n * 16 + lane] = y + r;
    }
}

// ---------------- K6: g2 at agent nodes only + relu + gather ----------------
// one wave per batch; lane owns value-channel pair (2*lane, 2*lane+1); head = lane>>4

__global__ __launch_bounds__(64) void k_g2(
    const float* __restrict__ ea, const float* __restrict__ a1, const int* __restrict__ agent,
    const float* __restrict__ Wq, const float* __restrict__ bq,
    const float* __restrict__ Wk, const float* __restrict__ bk,
    const float* __restrict__ Wv, const float* __restrict__ bv,
    const float* __restrict__ We, const float* __restrict__ Ws, const float* __restrict__ bs,
    const int* __restrict__ off, const int* __restrict__ csrc, const int* __restrict__ cge,
    float* __restrict__ out)
{
    int b = blockIdx.x;
    int lane = threadIdx.x;
    int n = b * Nn + agent[b];
    int v0 = lane * 2, v1i = lane * 2 + 1;

    float aa[16];
#pragma unroll
    for (int j = 0; j < 16; j++) aa[j] = a1[n * 16 + j];

    float wk0[16], wk1[16], wv0[16], wv1[16], we0[8], we1[8];
#pragma unroll
    for (int j = 0; j < 16; j++) {
        wk0[j] = Wk[v0 * 16 + j];  wk1[j] = Wk[v1i * 16 + j];
        wv0[j] = Wv[v0 * 16 + j];  wv1[j] = Wv[v1i * 16 + j];
    }
#pragma unroll
    for (int j = 0; j < 8; j++) { we0[j] = We[v0 * 8 + j]; we1[j] = We[v1i * 8 + j]; }

    float q0 = bq[v0], q1v = bq[v1i];
#pragma unroll
    for (int j = 0; j < 16; j++) {
        q0  = fmaf(Wq[v0 * 16 + j],  aa[j], q0);
        q1v = fmaf(Wq[v1i * 16 + j], aa[j], q1v);
    }

    int o0 = off[n];
    int deg = off[n + 1] - o0;

    float m = -1e30f, l = 0.f, a0 = 0.f, a1c = 0.f;
    for (int i = 0; i < deg; i++) {
        int src = csrc[o0 + i];
        int ge  = cge[o0 + i];
        float as[16];
#pragma unroll
        for (int j = 0; j < 16; j++) as[j] = a1[src * 16 + j];
        float eav[8];
#pragma unroll
        for (int j = 0; j < 8; j++) eav[j] = ea[(size_t)ge * 8 + j];

        float k0 = bk[v0], k1v = bk[v1i], vv0 = bv[v0], vv1 = bv[v1i];
#pragma unroll
        for (int j = 0; j < 16; j++) {
            k0  = fmaf(wk0[j], as[j], k0);
            k1v = fmaf(wk1[j], as[j], k1v);
            vv0 = fmaf(wv0[j], as[j], vv0);
            vv1 = fmaf(wv1[j], as[j], vv1);
        }
        float e0 = 0.f, e1 = 0.f;
#pragma unroll
        for (int j = 0; j < 8; j++) { e0 = fmaf(we0[j], eav[j], e0); e1 = fmaf(we1[j], eav[j], e1); }

        float t = q0 * (k0 + e0) + q1v * (k1v + e1);
        t += __shfl_xor(t, 1, 16);
        t += __shfl_xor(t, 2, 16);
        t += __shfl_xor(t, 4, 16);
        t += __shfl_xor(t, 8, 16);
        float logit = t * 0.17677669529663687f;  // / sqrt(32)
        float nm = fmaxf(m, logit);
        float sc = __expf(m - nm);
        float w  = __expf(logit - nm);
        a0  = a0 * sc + w * (vv0 + e0);
        a1c = a1c * sc + w * (vv1 + e1);
        l   = l * sc + w;
        m   = nm;
    }
    float y0 = (deg > 0) ? (a0 / l) : 0.f;
    float y1 = (deg > 0) ? (a1c / l) : 0.f;
    // sum heads (lanes lane, lane+16, lane+32, lane+48 hold same channel pair)
    y0 += __shfl_xor(y0, 16); y0 += __shfl_xor(y0, 32);
    y1 += __shfl_xor(y1, 16); y1 += __shfl_xor(y1, 32);
    y0 *= 0.25f; y1 *= 0.25f;

    if (lane < 16) {
        int c0 = lane * 2, c1 = lane * 2 + 1;
        float r0 = bs[c0], r1 = bs[c1];
#pragma unroll
        for (int j = 0; j < 16; j++) {
            r0 = fmaf(Ws[c0 * 16 + j], aa[j], r0);
            r1 = fmaf(Ws[c1 * 16 + j], aa[j], r1);
        }
        out[b * 32 + c0] = fmaxf(y0 + r0, 0.f);
        out[b * 32 + c1] = fmaxf(y1 + r1, 0.f);
    }
}

// ---------------- launch ----------------

extern "C" void kernel_launch(void* const* d_in, const int* in_sizes, int n_in,
                              void* d_out, int out_size, void* d_ws, size_t ws_size,
                              hipStream_t stream) {
    (void)in_sizes; (void)n_in; (void)out_size; (void)ws_size;
    const float* nf    = (const float*)d_in[0];
    const int*   ei    = (const int*)d_in[1];
    const float* ea    = (const float*)d_in[2];
    const int*   agent = (const int*)d_in[3];
    const float* ee    = (const float*)d_in[4];
    const float* W1    = (const float*)d_in[5];
    const float* b1    = (const float*)d_in[6];
    const float* W2    = (const float*)d_in[7];
    const float* b2    = (const float*)d_in[8];
    const float* W3    = (const float*)d_in[9];
    const float* b3    = (const float*)d_in[10];
    const float* lg    = (const float*)d_in[11];
    const float* lb    = (const float*)d_in[12];
    const float* g1Wq  = (const float*)d_in[13];
    const float* g1bq  = (const float*)d_in[14];
    const float* g1Wk  = (const float*)d_in[15];
    const float* g1bk  = (const float*)d_in[16];
    const float* g1Wv  = (const float*)d_in[17];
    const float* g1bv  = (const float*)d_in[18];
    const float* g1We  = (const float*)d_in[19];
    const float* g1Ws  = (const float*)d_in[20];
    const float* g1bs  = (const float*)d_in[21];
    const float* g2Wq  = (const float*)d_in[22];
    const float* g2bq  = (const float*)d_in[23];
    const float* g2Wk  = (const float*)d_in[24];
    const float* g2bk  = (const float*)d_in[25];
    const float* g2Wv  = (const float*)d_in[26];
    const float* g2bv  = (const float*)d_in[27];
    const float* g2We  = (const float*)d_in[28];
    const float* g2Ws  = (const float*)d_in[29];
    const float* g2bs  = (const float*)d_in[30];
    float* out = (float*)d_out;

    char* w = (char*)d_ws;
    int* pos  = (int*)w;  w += (size_t)NTOT * 4;
    int* off  = (int*)w;  w += (size_t)(NTOT + 1) * 4;
    int* csrc = (int*)w;  w += (size_t)ETOT * 4;
    int* cge  = (int*)w;  w += (size_t)ETOT * 4;
    w = (char*)(((uintptr_t)w + 15) & ~(uintptr_t)15);
    float* z  = (float*)w; w += (size_t)NTOT * 16 * 4;
    float* q1 = (float*)w; w += (size_t)NTOT * 64 * 4;
    float* k1 = (float*)w; w += (size_t)NTOT * 64 * 4;
    float* v1 = (float*)w; w += (size_t)NTOT * 64 * 4;
    float* a1 = (float*)w; w += (size_t)NTOT * 16 * 4;

    k_zero<<<dim3((NTOT + 255) / 256), dim3(256), 0, stream>>>(pos);
    k_count<<<dim3(ETOT / 256), dim3(256), 0, stream>>>(ei, pos);
    k_scan<<<dim3(1), dim3(256), 0, stream>>>(pos, off);
    k_fill<<<dim3(ETOT / 256), dim3(256), 0, stream>>>(ei, pos, csrc, cge);
    k_zqkv<<<dim3(NTOT / 4), dim3(256), 0, stream>>>(
        nf, ea, ee, W1, b1, W2, b2, W3, b3, lg, lb,
        g1Wq, g1bq, g1Wk, g1bk, g1Wv, g1bv,
        off, csrc, cge, z, q1, k1, v1);
    k_attn1<<<dim3(NTOT / 4), dim3(256), 0, stream>>>(
        ea, q1, k1, v1, g1We, g1Ws, g1bs, z, off, csrc, cge, a1);
    k_g2<<<dim3(Bb), dim3(64), 0, stream>>>(
        ea, a1, agent, g2Wq, g2bq, g2Wk, g2bk, g2Wv, g2bv, g2We, g2Ws, g2bs,
        off, csrc, cge, out);
}

// Round 2
// 266.089 us; speedup vs baseline: 1.2789x; 1.2789x over previous
//
#include <hip/hip_runtime.h>
#include <math.h>
#include <stdint.h>

#define Bb   128
#define Nn   100
#define Ee   3200
#define NTOT (Bb*Nn)    // 12800
#define ETOT (Bb*Ee)    // 409600

// ---------------- CSR build ----------------

__global__ __launch_bounds__(256) void k_zero(int* __restrict__ pos) {
    int i = blockIdx.x * 256 + threadIdx.x;
    if (i < NTOT) pos[i] = 0;
}

__global__ __launch_bounds__(256) void k_count(const int* __restrict__ ei, int* __restrict__ pos) {
    int ge = blockIdx.x * 256 + threadIdx.x;
    if (ge >= ETOT) return;
    int b = ge / Ee;
    int e = ge - b * Ee;
    int dst = ei[b * 2 * Ee + Ee + e] + b * Nn;
    atomicAdd(&pos[dst], 1);
}

__global__ __launch_bounds__(256) void k_scan(int* __restrict__ pos, int* __restrict__ off) {
    __shared__ int part[256];
    int t = threadIdx.x;
    const int per = NTOT / 256;  // 50
    int s = 0;
    for (int j = 0; j < per; j++) s += pos[t * per + j];
    part[t] = s;
    __syncthreads();
    for (int d = 1; d < 256; d <<= 1) {
        int v = (t >= d) ? part[t - d] : 0;
        __syncthreads();
        part[t] += v;
        __syncthreads();
    }
    int run = (t > 0) ? part[t - 1] : 0;
    for (int j = 0; j < per; j++) {
        int i = t * per + j;
        int cval = pos[i];
        off[i] = run;
        pos[i] = run;   // pos becomes the running write cursor for k_fill
        run += cval;
    }
    if (t == 255) off[NTOT] = run;
}

__global__ __launch_bounds__(256) void k_fill(const int* __restrict__ ei, int* __restrict__ pos,
                                              int2* __restrict__ cpair) {
    int ge = blockIdx.x * 256 + threadIdx.x;
    if (ge >= ETOT) return;
    int b = ge / Ee;
    int e = ge - b * Ee;
    int src = ei[b * 2 * Ee + e] + b * Nn;
    int dst = ei[b * 2 * Ee + Ee + e] + b * Nn;
    int idx = atomicAdd(&pos[dst], 1);
    cpair[idx] = make_int2(src, ge);
}

// ---------------- K_mlp: thread-owns-edge MLP, zero cross-lane ops ----------------

__device__ __forceinline__ void ln_reg(float* h, const float* __restrict__ g,
                                       const float* __restrict__ b) {
    float s = 0.f;
#pragma unroll
    for (int c = 0; c < 16; c++) s += h[c];
    float m = s * 0.0625f;
    float v = 0.f;
#pragma unroll
    for (int c = 0; c < 16; c++) { float d = h[c] - m; v += d * d; }
    float r = rsqrtf(v * 0.0625f + 1e-5f);
#pragma unroll
    for (int c = 0; c < 16; c++) h[c] = (h[c] - m) * r * g[c] + b[c];
}

__global__ __launch_bounds__(256) void k_mlp(
    const float* __restrict__ nf, const float* __restrict__ ea, const float* __restrict__ ee,
    const float* __restrict__ W1, const float* __restrict__ b1,
    const float* __restrict__ W2, const float* __restrict__ b2,
    const float* __restrict__ W3, const float* __restrict__ b3,
    const float* __restrict__ lg, const float* __restrict__ lb,
    const int2* __restrict__ cpair,
    float* __restrict__ h)
{
    int t = blockIdx.x * 256 + threadIdx.x;
    if (t >= ETOT) return;
    int2 p = cpair[t];
    int src = p.x, ge = p.y;
    int et = (int)nf[src];

    float in[12];
#pragma unroll
    for (int j = 0; j < 4; j++) in[j] = ee[et * 4 + j];
    const float4* ea4 = (const float4*)(ea + (size_t)ge * 8);
    float4 ua = ea4[0], ub = ea4[1];
    in[4] = ua.x; in[5] = ua.y; in[6] = ua.z; in[7] = ua.w;
    in[8] = ub.x; in[9] = ub.y; in[10] = ub.z; in[11] = ub.w;

    float h1[16];
#pragma unroll
    for (int c = 0; c < 16; c++) {
        float s = b1[c];
#pragma unroll
        for (int j = 0; j < 12; j++) s = fmaf(W1[c * 12 + j], in[j], s);
        h1[c] = fmaxf(s, 0.f);
    }
    ln_reg(h1, lg, lb);

    float h2[16];
#pragma unroll
    for (int c = 0; c < 16; c++) {
        float s = b2[c];
#pragma unroll
        for (int j = 0; j < 16; j++) s = fmaf(W2[c * 16 + j], h1[j], s);
        h2[c] = fmaxf(s, 0.f);
    }
    ln_reg(h2, lg, lb);

    float h3[16];
#pragma unroll
    for (int c = 0; c < 16; c++) {
        float s = b3[c];
#pragma unroll
        for (int j = 0; j < 16; j++) s = fmaf(W3[c * 16 + j], h2[j], s);
        h3[c] = fmaxf(s, 0.f);
    }
    ln_reg(h3, lg, lb);

    float4* hp = (float4*)(h + (size_t)t * 16);
    hp[0] = make_float4(h3[0], h3[1], h3[2], h3[3]);
    hp[1] = make_float4(h3[4], h3[5], h3[6], h3[7]);
    hp[2] = make_float4(h3[8], h3[9], h3[10], h3[11]);
    hp[3] = make_float4(h3[12], h3[13], h3[14], h3[15]);
}

// ---------------- K_zsum: per-node sum of h + q/k/v projection ----------------
// one wave per node; 4 edge slots x 16 channel lanes

__global__ __launch_bounds__(256) void k_zsum(
    const float* __restrict__ h,
    const float* __restrict__ Wq, const float* __restrict__ bq,
    const float* __restrict__ Wk, const float* __restrict__ bk,
    const float* __restrict__ Wv, const float* __restrict__ bv,
    const int* __restrict__ off,
    float* __restrict__ z, float* __restrict__ q1, float* __restrict__ k1, float* __restrict__ v1)
{
    int lane = threadIdx.x & 63;
    int wid  = threadIdx.x >> 6;
    int n    = blockIdx.x * 4 + wid;
    int c    = lane & 15;
    int slot = lane >> 4;

    int o0 = off[n];
    int deg = off[n + 1] - o0;

    float zp = 0.f;
    for (int base = 0; base < deg; base += 4) {
        int i = base + slot;
        float v = 0.f;
        if (i < deg) v = h[(size_t)(o0 + i) * 16 + c];
        zp += v;
    }
    zp += __shfl_xor(zp, 16);
    zp += __shfl_xor(zp, 32);

    if (lane < 16) z[n * 16 + lane] = zp;

    float aq = bq[lane], ak = bk[lane], av = bv[lane];
#pragma unroll
    for (int j = 0; j < 16; j++) {
        float zj = __shfl(zp, j, 16);
        aq = fmaf(Wq[lane * 16 + j], zj, aq);
        ak = fmaf(Wk[lane * 16 + j], zj, ak);
        av = fmaf(Wv[lane * 16 + j], zj, av);
    }
    q1[n * 64 + lane] = aq;
    k1[n * 64 + lane] = ak;
    v1[n * 64 + lane] = av;
}

// ---------------- K_attn1: g1 attention, online softmax, 2-edge unroll ----------------

__global__ __launch_bounds__(256) void k_attn1(
    const float* __restrict__ ea,
    const float* __restrict__ q1, const float* __restrict__ k1, const float* __restrict__ v1,
    const float* __restrict__ We, const float* __restrict__ Ws, const float* __restrict__ bs,
    const float* __restrict__ z,
    const int* __restrict__ off, const int2* __restrict__ cpair,
    float* __restrict__ a1)
{
    int lane = threadIdx.x & 63;
    int wid  = threadIdx.x >> 6;
    int n    = blockIdx.x * 4 + wid;

    float wer[8];
#pragma unroll
    for (int j = 0; j < 8; j++) wer[j] = We[lane * 8 + j];
    float ql = q1[n * 64 + lane];

    int o0 = off[n];
    int deg = off[n + 1] - o0;

    float m = -1e30f, l = 0.f, acc = 0.f;
    int i = 0;
    for (; i + 2 <= deg; i += 2) {
        int2 pA = cpair[o0 + i];
        int2 pB = cpair[o0 + i + 1];
        const float4* eaA = (const float4*)(ea + (size_t)pA.y * 8);
        const float4* eaB = (const float4*)(ea + (size_t)pB.y * 8);
        float4 a0v = eaA[0], a1v = eaA[1], b0v = eaB[0], b1v = eaB[1];
        float eA = wer[0] * a0v.x + wer[1] * a0v.y + wer[2] * a0v.z + wer[3] * a0v.w
                 + wer[4] * a1v.x + wer[5] * a1v.y + wer[6] * a1v.z + wer[7] * a1v.w;
        float eB = wer[0] * b0v.x + wer[1] * b0v.y + wer[2] * b0v.z + wer[3] * b0v.w
                 + wer[4] * b1v.x + wer[5] * b1v.y + wer[6] * b1v.z + wer[7] * b1v.w;
        float kA = k1[(size_t)pA.x * 64 + lane];
        float kB = k1[(size_t)pB.x * 64 + lane];
        float vA = v1[(size_t)pA.x * 64 + lane];
        float vB = v1[(size_t)pB.x * 64 + lane];
        float tA = ql * (kA + eA);
        float tB = ql * (kB + eB);
        tA += __shfl_xor(tA, 1, 16);  tB += __shfl_xor(tB, 1, 16);
        tA += __shfl_xor(tA, 2, 16);  tB += __shfl_xor(tB, 2, 16);
        tA += __shfl_xor(tA, 4, 16);  tB += __shfl_xor(tB, 4, 16);
        tA += __shfl_xor(tA, 8, 16);  tB += __shfl_xor(tB, 8, 16);
        float lA = tA * 0.25f;
        float lB = tB * 0.25f;
        float nm = fmaxf(m, fmaxf(lA, lB));
        float sc = __expf(m - nm);
        float wA = __expf(lA - nm);
        float wB = __expf(lB - nm);
        acc = acc * sc + wA * (vA + eA) + wB * (vB + eB);
        l   = l * sc + wA + wB;
        m   = nm;
    }
    for (; i < deg; i++) {
        int2 p = cpair[o0 + i];
        const float4* ea4 = (const float4*)(ea + (size_t)p.y * 8);
        float4 u0 = ea4[0], u1 = ea4[1];
        float el = wer[0] * u0.x + wer[1] * u0.y + wer[2] * u0.z + wer[3] * u0.w
                 + wer[4] * u1.x + wer[5] * u1.y + wer[6] * u1.z + wer[7] * u1.w;
        float kl = k1[(size_t)p.x * 64 + lane];
        float t = ql * (kl + el);
        t += __shfl_xor(t, 1, 16);
        t += __shfl_xor(t, 2, 16);
        t += __shfl_xor(t, 4, 16);
        t += __shfl_xor(t, 8, 16);
        float logit = t * 0.25f;
        float nm = fmaxf(m, logit);
        float sc = __expf(m - nm);
        float w  = __expf(logit - nm);
        float vl = v1[(size_t)p.x * 64 + lane];
        acc = acc * sc + w * (vl + el);
        l   = l * sc + w;
        m   = nm;
    }
    float y = (deg > 0) ? (acc / l) : 0.f;
    y += __shfl_xor(y, 16);
    y += __shfl_xor(y, 32);
    y *= 0.25f;

    if (lane < 16) {
        float r = bs[lane];
#pragma unroll
        for (int j = 0; j < 16; j++) r = fmaf(Ws[lane * 16 + j], z[n * 16 + j], r);
        a1[n * 16 + lane] = y + r;
    }
}

// ---------------- K_g2: agent nodes only, 4 waves/batch + LDS merge ----------------

__global__ __launch_bounds__(256) void k_g2(
    const float* __restrict__ ea, const float* __restrict__ a1, const int* __restrict__ agent,
    const float* __restrict__ Wq, const float* __restrict__ bq,
    const float* __restrict__ Wk, const float* __restrict__ bk,
    const float* __restrict__ Wv, const float* __restrict__ bv,
    const float* __restrict__ We, const float* __restrict__ Ws, const float* __restrict__ bs,
    const int* __restrict__ off, const int2* __restrict__ cpair,
    float* __restrict__ out)
{
    __shared__ float sm[4][64], sl[4][64], sa0[4][64], sa1[4][64];
    int b = blockIdx.x;
    int lane = threadIdx.x & 63;
    int w = threadIdx.x >> 6;
    int n = b * Nn + agent[b];
    int v0 = lane * 2, v1i = lane * 2 + 1;

    float aa[16];
#pragma unroll
    for (int j = 0; j < 16; j++) aa[j] = a1[n * 16 + j];

    float wk0[16], wk1[16], wv0[16], wv1[16], we0[8], we1[8];
#pragma unroll
    for (int j = 0; j < 16; j++) {
        wk0[j] = Wk[v0 * 16 + j];  wk1[j] = Wk[v1i * 16 + j];
        wv0[j] = Wv[v0 * 16 + j];  wv1[j] = Wv[v1i * 16 + j];
    }
#pragma unroll
    for (int j = 0; j < 8; j++) { we0[j] = We[v0 * 8 + j]; we1[j] = We[v1i * 8 + j]; }

    float q0 = bq[v0], q1v = bq[v1i];
#pragma unroll
    for (int j = 0; j < 16; j++) {
        q0  = fmaf(Wq[v0 * 16 + j],  aa[j], q0);
        q1v = fmaf(Wq[v1i * 16 + j], aa[j], q1v);
    }

    int o0 = off[n];
    int deg = off[n + 1] - o0;

    float m = -1e30f, l = 0.f, a0 = 0.f, a1c = 0.f;
    for (int i = w; i < deg; i += 4) {
        int2 p = cpair[o0 + i];
        int src = p.x, ge = p.y;
        float as[16];
#pragma unroll
        for (int j = 0; j < 16; j++) as[j] = a1[src * 16 + j];
        const float4* ea4 = (const float4*)(ea + (size_t)ge * 8);
        float4 u0 = ea4[0], u1 = ea4[1];
        float eav[8] = {u0.x, u0.y, u0.z, u0.w, u1.x, u1.y, u1.z, u1.w};

        float k0 = bk[v0], k1v = bk[v1i], vv0 = bv[v0], vv1 = bv[v1i];
#pragma unroll
        for (int j = 0; j < 16; j++) {
            k0  = fmaf(wk0[j], as[j], k0);
            k1v = fmaf(wk1[j], as[j], k1v);
            vv0 = fmaf(wv0[j], as[j], vv0);
            vv1 = fmaf(wv1[j], as[j], vv1);
        }
        float e0 = 0.f, e1 = 0.f;
#pragma unroll
        for (int j = 0; j < 8; j++) { e0 = fmaf(we0[j], eav[j], e0); e1 = fmaf(we1[j], eav[j], e1); }

        float t = q0 * (k0 + e0) + q1v * (k1v + e1);
        t += __shfl_xor(t, 1, 16);
        t += __shfl_xor(t, 2, 16);
        t += __shfl_xor(t, 4, 16);
        t += __shfl_xor(t, 8, 16);
        float logit = t * 0.17677669529663687f;  // / sqrt(32)
        float nm = fmaxf(m, logit);
        float sc = __expf(m - nm);
        float wgt = __expf(logit - nm);
        a0  = a0 * sc + wgt * (vv0 + e0);
        a1c = a1c * sc + wgt * (vv1 + e1);
        l   = l * sc + wgt;
        m   = nm;
    }
    sm[w][lane] = m; sl[w][lane] = l; sa0[w][lane] = a0; sa1[w][lane] = a1c;
    __syncthreads();
    if (w == 0) {
        float M = fmaxf(fmaxf(sm[0][lane], sm[1][lane]), fmaxf(sm[2][lane], sm[3][lane]));
        float L = 0.f, A0 = 0.f, A1 = 0.f;
#pragma unroll
        for (int ww = 0; ww < 4; ww++) {
            float sc = __expf(sm[ww][lane] - M);
            L  += sc * sl[ww][lane];
            A0 += sc * sa0[ww][lane];
            A1 += sc * sa1[ww][lane];
        }
        float y0 = (deg > 0) ? (A0 / L) : 0.f;
        float y1 = (deg > 0) ? (A1 / L) : 0.f;
        y0 += __shfl_xor(y0, 16); y0 += __shfl_xor(y0, 32);
        y1 += __shfl_xor(y1, 16); y1 += __shfl_xor(y1, 32);
        y0 *= 0.25f; y1 *= 0.25f;

        if (lane < 16) {
            int c0 = lane * 2, c1 = lane * 2 + 1;
            float r0 = bs[c0], r1 = bs[c1];
#pragma unroll
            for (int j = 0; j < 16; j++) {
                r0 = fmaf(Ws[c0 * 16 + j], aa[j], r0);
                r1 = fmaf(Ws[c1 * 16 + j], aa[j], r1);
            }
            out[b * 32 + c0] = fmaxf(y0 + r0, 0.f);
            out[b * 32 + c1] = fmaxf(y1 + r1, 0.f);
        }
    }
}

// ---------------- launch ----------------

extern "C" void kernel_launch(void* const* d_in, const int* in_sizes, int n_in,
                              void* d_out, int out_size, void* d_ws, size_t ws_size,
                              hipStream_t stream) {
    (void)in_sizes; (void)n_in; (void)out_size; (void)ws_size;
    const float* nf    = (const float*)d_in[0];
    const int*   ei    = (const int*)d_in[1];
    const float* ea    = (const float*)d_in[2];
    const int*   agent = (const int*)d_in[3];
    const float* ee    = (const float*)d_in[4];
    const float* W1    = (const float*)d_in[5];
    const float* b1    = (const float*)d_in[6];
    const float* W2    = (const float*)d_in[7];
    const float* b2    = (const float*)d_in[8];
    const float* W3    = (const float*)d_in[9];
    const float* b3    = (const float*)d_in[10];
    const float* lg    = (const float*)d_in[11];
    const float* lb    = (const float*)d_in[12];
    const float* g1Wq  = (const float*)d_in[13];
    const float* g1bq  = (const float*)d_in[14];
    const float* g1Wk  = (const float*)d_in[15];
    const float* g1bk  = (const float*)d_in[16];
    const float* g1Wv  = (const float*)d_in[17];
    const float* g1bv  = (const float*)d_in[18];
    const float* g1We  = (const float*)d_in[19];
    const float* g1Ws  = (const float*)d_in[20];
    const float* g1bs  = (const float*)d_in[21];
    const float* g2Wq  = (const float*)d_in[22];
    const float* g2bq  = (const float*)d_in[23];
    const float* g2Wk  = (const float*)d_in[24];
    const float* g2bk  = (const float*)d_in[25];
    const float* g2Wv  = (const float*)d_in[26];
    const float* g2bv  = (const float*)d_in[27];
    const float* g2We  = (const float*)d_in[28];
    const float* g2Ws  = (const float*)d_in[29];
    const float* g2bs  = (const float*)d_in[30];
    float* out = (float*)d_out;

    char* w = (char*)d_ws;
    int* pos   = (int*)w;  w += (size_t)NTOT * 4;
    int* off   = (int*)w;  w += (size_t)(NTOT + 4) * 4;
    w = (char*)(((uintptr_t)w + 15) & ~(uintptr_t)15);
    int2* cpair = (int2*)w; w += (size_t)ETOT * 8;
    float* h   = (float*)w; w += (size_t)ETOT * 16 * 4;
    float* z   = (float*)w; w += (size_t)NTOT * 16 * 4;
    float* q1  = (float*)w; w += (size_t)NTOT * 64 * 4;
    float* k1  = (float*)w; w += (size_t)NTOT * 64 * 4;
    float* v1  = (float*)w; w += (size_t)NTOT * 64 * 4;
    float* a1  = (float*)w; w += (size_t)NTOT * 16 * 4;

    k_zero<<<dim3((NTOT + 255) / 256), dim3(256), 0, stream>>>(pos);
    k_count<<<dim3(ETOT / 256), dim3(256), 0, stream>>>(ei, pos);
    k_scan<<<dim3(1), dim3(256), 0, stream>>>(pos, off);
    k_fill<<<dim3(ETOT / 256), dim3(256), 0, stream>>>(ei, pos, cpair);
    k_mlp<<<dim3(ETOT / 256), dim3(256), 0, stream>>>(
        nf, ea, ee, W1, b1, W2, b2, W3, b3, lg, lb, cpair, h);
    k_zsum<<<dim3(NTOT / 4), dim3(256), 0, stream>>>(
        h, g1Wq, g1bq, g1Wk, g1bk, g1Wv, g1bv, off, z, q1, k1, v1);
    k_attn1<<<dim3(NTOT / 4), dim3(256), 0, stream>>>(
        ea, q1, k1, v1, g1We, g1Ws, g1bs, z, off, cpair, a1);
    k_g2<<<dim3(Bb), dim3(256), 0, stream>>>(
        ea, a1, agent, g2Wq, g2bq, g2Wk, g2bk, g2Wv, g2bv, g2We, g2Ws, g2bs,
        off, cpair, out);
}

// Round 3
// 240.864 us; speedup vs baseline: 1.4129x; 1.1047x over previous
//
#include <hip/hip_runtime.h>
#include <math.h>
#include <stdint.h>

#define Bb   128
#define Nn   100
#define Ee   3200
#define NTOT (Bb*Nn)    // 12800
#define ETOT (Bb*Ee)    // 409600

// XCD swizzle: blockIdx&7 -> XCD (dispatch is round-robin over 8 XCDs).
// XCD x owns batches [16x, 16x+16): all producers/consumers of a batch's
// data land on the same XCD -> L2-resident intermediates. Perf-only heuristic.

// ---------------- CSR build ----------------

__global__ __launch_bounds__(256) void k_zero(int* __restrict__ p) {
    int i = blockIdx.x * 256 + threadIdx.x;
    if (i < 2 * NTOT) p[i] = 0;   // pos + mark
}

__global__ __launch_bounds__(256) void k_count(const int* __restrict__ ei, int* __restrict__ pos) {
    int ge = (blockIdx.x & 7) * (ETOT / 8) + (blockIdx.x >> 3) * 256 + threadIdx.x;
    int b = ge / Ee;
    int e = ge - b * Ee;
    int dst = ei[b * 2 * Ee + Ee + e] + b * Nn;
    atomicAdd(&pos[dst], 1);
}

__global__ __launch_bounds__(256) void k_scan(int* __restrict__ pos, int* __restrict__ off) {
    __shared__ int part[256];
    int t = threadIdx.x;
    const int per = NTOT / 256;  // 50
    int s = 0;
#pragma unroll
    for (int j = 0; j < per; j++) s += pos[t * per + j];
    part[t] = s;
    __syncthreads();
    for (int d = 1; d < 256; d <<= 1) {
        int v = (t >= d) ? part[t - d] : 0;
        __syncthreads();
        part[t] += v;
        __syncthreads();
    }
    int run = (t > 0) ? part[t - 1] : 0;
    for (int j = 0; j < per; j++) {
        int i = t * per + j;
        int cval = pos[i];
        off[i] = run;
        pos[i] = run;   // pos becomes the running write cursor for k_fill
        run += cval;
    }
    if (t == 255) off[NTOT] = run;
}

__global__ __launch_bounds__(256) void k_fill(const int* __restrict__ ei, int* __restrict__ pos,
                                              int2* __restrict__ cpair) {
    int ge = (blockIdx.x & 7) * (ETOT / 8) + (blockIdx.x >> 3) * 256 + threadIdx.x;
    int b = ge / Ee;
    int e = ge - b * Ee;
    int src = ei[b * 2 * Ee + e] + b * Nn;
    int dst = ei[b * 2 * Ee + Ee + e] + b * Nn;
    int idx = atomicAdd(&pos[dst], 1);
    cpair[idx] = make_int2(src, ge);
}

// ---------------- K_mark: nodes whose a1 is actually needed ----------------
// needed = agent nodes + srcs of agent in-edges (~33% of nodes)

__global__ __launch_bounds__(64) void k_mark(const int* __restrict__ agent,
                                             const int* __restrict__ off,
                                             const int2* __restrict__ cpair,
                                             int* __restrict__ mark) {
    int b = ((blockIdx.x & 7) << 4) + (blockIdx.x >> 3);
    int lane = threadIdx.x;
    int n = b * Nn + agent[b];
    if (lane == 0) mark[n] = 1;
    int o0 = off[n];
    int deg = off[n + 1] - o0;
    for (int i = lane; i < deg; i += 64) mark[cpair[o0 + i].x] = 1;
}

// ---------------- K_mlp: thread-owns-edge MLP ----------------

__device__ __forceinline__ void ln_reg(float* h, const float* __restrict__ g,
                                       const float* __restrict__ b) {
    float s = 0.f;
#pragma unroll
    for (int c = 0; c < 16; c++) s += h[c];
    float m = s * 0.0625f;
    float v = 0.f;
#pragma unroll
    for (int c = 0; c < 16; c++) { float d = h[c] - m; v += d * d; }
    float r = rsqrtf(v * 0.0625f + 1e-5f);
#pragma unroll
    for (int c = 0; c < 16; c++) h[c] = (h[c] - m) * r * g[c] + b[c];
}

__global__ __launch_bounds__(256) void k_mlp(
    const float* __restrict__ nf, const float* __restrict__ ea, const float* __restrict__ ee,
    const float* __restrict__ W1, const float* __restrict__ b1,
    const float* __restrict__ W2, const float* __restrict__ b2,
    const float* __restrict__ W3, const float* __restrict__ b3,
    const float* __restrict__ lg, const float* __restrict__ lb,
    const int2* __restrict__ cpair,
    float* __restrict__ h)
{
    int t = (blockIdx.x & 7) * (ETOT / 8) + (blockIdx.x >> 3) * 256 + threadIdx.x;
    int2 p = cpair[t];
    int src = p.x, ge = p.y;
    int et = (int)nf[src];

    float in[12];
#pragma unroll
    for (int j = 0; j < 4; j++) in[j] = ee[et * 4 + j];
    const float4* ea4 = (const float4*)(ea + (size_t)ge * 8);
    float4 ua = ea4[0], ub = ea4[1];
    in[4] = ua.x; in[5] = ua.y; in[6] = ua.z; in[7] = ua.w;
    in[8] = ub.x; in[9] = ub.y; in[10] = ub.z; in[11] = ub.w;

    float h1[16];
#pragma unroll
    for (int c = 0; c < 16; c++) {
        float s = b1[c];
#pragma unroll
        for (int j = 0; j < 12; j++) s = fmaf(W1[c * 12 + j], in[j], s);
        h1[c] = fmaxf(s, 0.f);
    }
    ln_reg(h1, lg, lb);

    float h2[16];
#pragma unroll
    for (int c = 0; c < 16; c++) {
        float s = b2[c];
#pragma unroll
        for (int j = 0; j < 16; j++) s = fmaf(W2[c * 16 + j], h1[j], s);
        h2[c] = fmaxf(s, 0.f);
    }
    ln_reg(h2, lg, lb);

    float h3[16];
#pragma unroll
    for (int c = 0; c < 16; c++) {
        float s = b3[c];
#pragma unroll
        for (int j = 0; j < 16; j++) s = fmaf(W3[c * 16 + j], h2[j], s);
        h3[c] = fmaxf(s, 0.f);
    }
    ln_reg(h3, lg, lb);

    float4* hp = (float4*)(h + (size_t)t * 16);
    hp[0] = make_float4(h3[0], h3[1], h3[2], h3[3]);
    hp[1] = make_float4(h3[4], h3[5], h3[6], h3[7]);
    hp[2] = make_float4(h3[8], h3[9], h3[10], h3[11]);
    hp[3] = make_float4(h3[12], h3[13], h3[14], h3[15]);
}

// ---------------- K_zsum: per-node sum of h + q/k/v projection ----------------

__global__ __launch_bounds__(256) void k_zsum(
    const float* __restrict__ h,
    const float* __restrict__ Wq, const float* __restrict__ bq,
    const float* __restrict__ Wk, const float* __restrict__ bk,
    const float* __restrict__ Wv, const float* __restrict__ bv,
    const int* __restrict__ off,
    float* __restrict__ z, float* __restrict__ q1, float* __restrict__ k1, float* __restrict__ v1)
{
    int lane = threadIdx.x & 63;
    int wid  = threadIdx.x >> 6;
    int n    = (blockIdx.x & 7) * (NTOT / 8) + (blockIdx.x >> 3) * 4 + wid;
    int c    = lane & 15;
    int slot = lane >> 4;

    int o0 = off[n];
    int deg = off[n + 1] - o0;

    float zp = 0.f;
    for (int base = 0; base < deg; base += 4) {
        int i = base + slot;
        float v = 0.f;
        if (i < deg) v = h[(size_t)(o0 + i) * 16 + c];
        zp += v;
    }
    zp += __shfl_xor(zp, 16);
    zp += __shfl_xor(zp, 32);

    if (lane < 16) z[n * 16 + lane] = zp;

    float aq = bq[lane], ak = bk[lane], av = bv[lane];
#pragma unroll
    for (int j = 0; j < 16; j++) {
        float zj = __shfl(zp, j, 16);
        aq = fmaf(Wq[lane * 16 + j], zj, aq);
        ak = fmaf(Wk[lane * 16 + j], zj, ak);
        av = fmaf(Wv[lane * 16 + j], zj, av);
    }
    q1[n * 64 + lane] = aq;
    k1[n * 64 + lane] = ak;
    v1[n * 64 + lane] = av;
}

// ---------------- K_attn1: g1 attention at marked nodes only ----------------

__global__ __launch_bounds__(256) void k_attn1(
    const float* __restrict__ ea,
    const float* __restrict__ q1, const float* __restrict__ k1, const float* __restrict__ v1,
    const float* __restrict__ We, const float* __restrict__ Ws, const float* __restrict__ bs,
    const float* __restrict__ z, const int* __restrict__ mark,
    const int* __restrict__ off, const int2* __restrict__ cpair,
    float* __restrict__ a1)
{
    int lane = threadIdx.x & 63;
    int wid  = threadIdx.x >> 6;
    int n    = (blockIdx.x & 7) * (NTOT / 8) + (blockIdx.x >> 3) * 4 + wid;

    if (!mark[n]) return;   // wave-uniform: a1[n] is never read

    float wer[8];
#pragma unroll
    for (int j = 0; j < 8; j++) wer[j] = We[lane * 8 + j];
    float ql = q1[n * 64 + lane];

    int o0 = off[n];
    int deg = off[n + 1] - o0;

    float m = -1e30f, l = 0.f, acc = 0.f;
    int i = 0;
    for (; i + 2 <= deg; i += 2) {
        int2 pA = cpair[o0 + i];
        int2 pB = cpair[o0 + i + 1];
        const float4* eaA = (const float4*)(ea + (size_t)pA.y * 8);
        const float4* eaB = (const float4*)(ea + (size_t)pB.y * 8);
        float4 a0v = eaA[0], a1v = eaA[1], b0v = eaB[0], b1v = eaB[1];
        float eA = wer[0] * a0v.x + wer[1] * a0v.y + wer[2] * a0v.z + wer[3] * a0v.w
                 + wer[4] * a1v.x + wer[5] * a1v.y + wer[6] * a1v.z + wer[7] * a1v.w;
        float eB = wer[0] * b0v.x + wer[1] * b0v.y + wer[2] * b0v.z + wer[3] * b0v.w
                 + wer[4] * b1v.x + wer[5] * b1v.y + wer[6] * b1v.z + wer[7] * b1v.w;
        float kA = k1[(size_t)pA.x * 64 + lane];
        float kB = k1[(size_t)pB.x * 64 + lane];
        float vA = v1[(size_t)pA.x * 64 + lane];
        float vB = v1[(size_t)pB.x * 64 + lane];
        float tA = ql * (kA + eA);
        float tB = ql * (kB + eB);
        tA += __shfl_xor(tA, 1, 16);  tB += __shfl_xor(tB, 1, 16);
        tA += __shfl_xor(tA, 2, 16);  tB += __shfl_xor(tB, 2, 16);
        tA += __shfl_xor(tA, 4, 16);  tB += __shfl_xor(tB, 4, 16);
        tA += __shfl_xor(tA, 8, 16);  tB += __shfl_xor(tB, 8, 16);
        float lA = tA * 0.25f;
        float lB = tB * 0.25f;
        float nm = fmaxf(m, fmaxf(lA, lB));
        float sc = __expf(m - nm);
        float wA = __expf(lA - nm);
        float wB = __expf(lB - nm);
        acc = acc * sc + wA * (vA + eA) + wB * (vB + eB);
        l   = l * sc + wA + wB;
        m   = nm;
    }
    for (; i < deg; i++) {
        int2 p = cpair[o0 + i];
        const float4* ea4 = (const float4*)(ea + (size_t)p.y * 8);
        float4 u0 = ea4[0], u1 = ea4[1];
        float el = wer[0] * u0.x + wer[1] * u0.y + wer[2] * u0.z + wer[3] * u0.w
                 + wer[4] * u1.x + wer[5] * u1.y + wer[6] * u1.z + wer[7] * u1.w;
        float kl = k1[(size_t)p.x * 64 + lane];
        float t = ql * (kl + el);
        t += __shfl_xor(t, 1, 16);
        t += __shfl_xor(t, 2, 16);
        t += __shfl_xor(t, 4, 16);
        t += __shfl_xor(t, 8, 16);
        float logit = t * 0.25f;
        float nm = fmaxf(m, logit);
        float sc = __expf(m - nm);
        float w  = __expf(logit - nm);
        float vl = v1[(size_t)p.x * 64 + lane];
        acc = acc * sc + w * (vl + el);
        l   = l * sc + w;
        m   = nm;
    }
    float y = (deg > 0) ? (acc / l) : 0.f;
    y += __shfl_xor(y, 16);
    y += __shfl_xor(y, 32);
    y *= 0.25f;

    if (lane < 16) {
        float r = bs[lane];
#pragma unroll
        for (int j = 0; j < 16; j++) r = fmaf(Ws[lane * 16 + j], z[n * 16 + j], r);
        a1[n * 16 + lane] = y + r;
    }
}

// ---------------- K_g2: agent nodes only, 4 waves/batch + LDS merge ----------------

__global__ __launch_bounds__(256) void k_g2(
    const float* __restrict__ ea, const float* __restrict__ a1, const int* __restrict__ agent,
    const float* __restrict__ Wq, const float* __restrict__ bq,
    const float* __restrict__ Wk, const float* __restrict__ bk,
    const float* __restrict__ Wv, const float* __restrict__ bv,
    const float* __restrict__ We, const float* __restrict__ Ws, const float* __restrict__ bs,
    const int* __restrict__ off, const int2* __restrict__ cpair,
    float* __restrict__ out)
{
    __shared__ float sm[4][64], sl[4][64], sa0[4][64], sa1[4][64];
    int b = ((blockIdx.x & 7) << 4) + (blockIdx.x >> 3);
    int lane = threadIdx.x & 63;
    int w = threadIdx.x >> 6;
    int n = b * Nn + agent[b];
    int v0 = lane * 2, v1i = lane * 2 + 1;

    float aa[16];
#pragma unroll
    for (int j = 0; j < 16; j++) aa[j] = a1[n * 16 + j];

    float wk0[16], wk1[16], wv0[16], wv1[16], we0[8], we1[8];
#pragma unroll
    for (int j = 0; j < 16; j++) {
        wk0[j] = Wk[v0 * 16 + j];  wk1[j] = Wk[v1i * 16 + j];
        wv0[j] = Wv[v0 * 16 + j];  wv1[j] = Wv[v1i * 16 + j];
    }
#pragma unroll
    for (int j = 0; j < 8; j++) { we0[j] = We[v0 * 8 + j]; we1[j] = We[v1i * 8 + j]; }

    float q0 = bq[v0], q1v = bq[v1i];
#pragma unroll
    for (int j = 0; j < 16; j++) {
        q0  = fmaf(Wq[v0 * 16 + j],  aa[j], q0);
        q1v = fmaf(Wq[v1i * 16 + j], aa[j], q1v);
    }

    int o0 = off[n];
    int deg = off[n + 1] - o0;

    float m = -1e30f, l = 0.f, a0 = 0.f, a1c = 0.f;
    for (int i = w; i < deg; i += 4) {
        int2 p = cpair[o0 + i];
        int src = p.x, ge = p.y;
        float as[16];
#pragma unroll
        for (int j = 0; j < 16; j++) as[j] = a1[src * 16 + j];
        const float4* ea4 = (const float4*)(ea + (size_t)ge * 8);
        float4 u0 = ea4[0], u1 = ea4[1];
        float eav[8] = {u0.x, u0.y, u0.z, u0.w, u1.x, u1.y, u1.z, u1.w};

        float k0 = bk[v0], k1v = bk[v1i], vv0 = bv[v0], vv1 = bv[v1i];
#pragma unroll
        for (int j = 0; j < 16; j++) {
            k0  = fmaf(wk0[j], as[j], k0);
            k1v = fmaf(wk1[j], as[j], k1v);
            vv0 = fmaf(wv0[j], as[j], vv0);
            vv1 = fmaf(wv1[j], as[j], vv1);
        }
        float e0 = 0.f, e1 = 0.f;
#pragma unroll
        for (int j = 0; j < 8; j++) { e0 = fmaf(we0[j], eav[j], e0); e1 = fmaf(we1[j], eav[j], e1); }

        float t = q0 * (k0 + e0) + q1v * (k1v + e1);
        t += __shfl_xor(t, 1, 16);
        t += __shfl_xor(t, 2, 16);
        t += __shfl_xor(t, 4, 16);
        t += __shfl_xor(t, 8, 16);
        float logit = t * 0.17677669529663687f;  // / sqrt(32)
        float nm = fmaxf(m, logit);
        float sc = __expf(m - nm);
        float wgt = __expf(logit - nm);
        a0  = a0 * sc + wgt * (vv0 + e0);
        a1c = a1c * sc + wgt * (vv1 + e1);
        l   = l * sc + wgt;
        m   = nm;
    }
    sm[w][lane] = m; sl[w][lane] = l; sa0[w][lane] = a0; sa1[w][lane] = a1c;
    __syncthreads();
    if (w == 0) {
        float M = fmaxf(fmaxf(sm[0][lane], sm[1][lane]), fmaxf(sm[2][lane], sm[3][lane]));
        float L = 0.f, A0 = 0.f, A1 = 0.f;
#pragma unroll
        for (int ww = 0; ww < 4; ww++) {
            float sc = __expf(sm[ww][lane] - M);
            L  += sc * sl[ww][lane];
            A0 += sc * sa0[ww][lane];
            A1 += sc * sa1[ww][lane];
        }
        float y0 = (deg > 0) ? (A0 / L) : 0.f;
        float y1 = (deg > 0) ? (A1 / L) : 0.f;
        y0 += __shfl_xor(y0, 16); y0 += __shfl_xor(y0, 32);
        y1 += __shfl_xor(y1, 16); y1 += __shfl_xor(y1, 32);
        y0 *= 0.25f; y1 *= 0.25f;

        if (lane < 16) {
            int c0 = lane * 2, c1 = lane * 2 + 1;
            float r0 = bs[c0], r1 = bs[c1];
#pragma unroll
            for (int j = 0; j < 16; j++) {
                r0 = fmaf(Ws[c0 * 16 + j], aa[j], r0);
                r1 = fmaf(Ws[c1 * 16 + j], aa[j], r1);
            }
            out[b * 32 + c0] = fmaxf(y0 + r0, 0.f);
            out[b * 32 + c1] = fmaxf(y1 + r1, 0.f);
        }
    }
}

// ---------------- launch ----------------

extern "C" void kernel_launch(void* const* d_in, const int* in_sizes, int n_in,
                              void* d_out, int out_size, void* d_ws, size_t ws_size,
                              hipStream_t stream) {
    (void)in_sizes; (void)n_in; (void)out_size; (void)ws_size;
    const float* nf    = (const float*)d_in[0];
    const int*   ei    = (const int*)d_in[1];
    const float* ea    = (const float*)d_in[2];
    const int*   agent = (const int*)d_in[3];
    const float* ee    = (const float*)d_in[4];
    const float* W1    = (const float*)d_in[5];
    const float* b1    = (const float*)d_in[6];
    const float* W2    = (const float*)d_in[7];
    const float* b2    = (const float*)d_in[8];
    const float* W3    = (const float*)d_in[9];
    const float* b3    = (const float*)d_in[10];
    const float* lg    = (const float*)d_in[11];
    const float* lb    = (const float*)d_in[12];
    const float* g1Wq  = (const float*)d_in[13];
    const float* g1bq  = (const float*)d_in[14];
    const float* g1Wk  = (const float*)d_in[15];
    const float* g1bk  = (const float*)d_in[16];
    const float* g1Wv  = (const float*)d_in[17];
    const float* g1bv  = (const float*)d_in[18];
    const float* g1We  = (const float*)d_in[19];
    const float* g1Ws  = (const float*)d_in[20];
    const float* g1bs  = (const float*)d_in[21];
    const float* g2Wq  = (const float*)d_in[22];
    const float* g2bq  = (const float*)d_in[23];
    const float* g2Wk  = (const float*)d_in[24];
    const float* g2bk  = (const float*)d_in[25];
    const float* g2Wv  = (const float*)d_in[26];
    const float* g2bv  = (const float*)d_in[27];
    const float* g2We  = (const float*)d_in[28];
    const float* g2Ws  = (const float*)d_in[29];
    const float* g2bs  = (const float*)d_in[30];
    float* out = (float*)d_out;

    char* w = (char*)d_ws;
    int* pos   = (int*)w;  w += (size_t)NTOT * 4;
    int* mark  = (int*)w;  w += (size_t)NTOT * 4;
    int* off   = (int*)w;  w += (size_t)(NTOT + 4) * 4;
    w = (char*)(((uintptr_t)w + 15) & ~(uintptr_t)15);
    int2* cpair = (int2*)w; w += (size_t)ETOT * 8;
    float* h   = (float*)w; w += (size_t)ETOT * 16 * 4;
    float* z   = (float*)w; w += (size_t)NTOT * 16 * 4;
    float* q1  = (float*)w; w += (size_t)NTOT * 64 * 4;
    float* k1  = (float*)w; w += (size_t)NTOT * 64 * 4;
    float* v1  = (float*)w; w += (size_t)NTOT * 64 * 4;
    float* a1  = (float*)w; w += (size_t)NTOT * 16 * 4;

    k_zero<<<dim3((2 * NTOT + 255) / 256), dim3(256), 0, stream>>>(pos);
    k_count<<<dim3(ETOT / 256), dim3(256), 0, stream>>>(ei, pos);
    k_scan<<<dim3(1), dim3(256), 0, stream>>>(pos, off);
    k_fill<<<dim3(ETOT / 256), dim3(256), 0, stream>>>(ei, pos, cpair);
    k_mark<<<dim3(Bb), dim3(64), 0, stream>>>(agent, off, cpair, mark);
    k_mlp<<<dim3(ETOT / 256), dim3(256), 0, stream>>>(
        nf, ea, ee, W1, b1, W2, b2, W3, b3, lg, lb, cpair, h);
    k_zsum<<<dim3(NTOT / 4), dim3(256), 0, stream>>>(
        h, g1Wq, g1bq, g1Wk, g1bk, g1Wv, g1bv, off, z, q1, k1, v1);
    k_attn1<<<dim3(NTOT / 4), dim3(256), 0, stream>>>(
        ea, q1, k1, v1, g1We, g1Ws, g1bs, z, mark, off, cpair, a1);
    k_g2<<<dim3(Bb), dim3(256), 0, stream>>>(
        ea, a1, agent, g2Wq, g2bq, g2Wk, g2bk, g2Wv, g2bv, g2We, g2Ws, g2bs,
        off, cpair, out);
}

// Round 4
// 204.600 us; speedup vs baseline: 1.6633x; 1.1772x over previous
//
#include <hip/hip_runtime.h>
#include <math.h>
#include <stdint.h>

#define Bb   128
#define Nn   100
#define Ee   3200
#define NTOT (Bb*Nn)    // 12800
#define ETOT (Bb*Ee)    // 409600

// XCD swizzle: blockIdx&7 -> XCD (dispatch round-robin over 8 XCDs).
// XCD x owns batches [16x,16x+16): producers and consumers of a batch's
// data land on the same XCD -> L2-resident intermediates. Perf-only.

// ---------------- K_csr: per-batch CSR build + mark, all-LDS ----------------
// Replaces k_zero/k_count/k_scan/k_fill/k_mark (5 launches -> 1, no global atomics)

__global__ __launch_bounds__(256) void k_csr(const int* __restrict__ ei,
                                             const int* __restrict__ agent,
                                             int* __restrict__ off,
                                             int2* __restrict__ cpair,
                                             int* __restrict__ mark)
{
    int b = ((blockIdx.x & 7) << 4) + (blockIdx.x >> 3);
    int t = threadIdx.x;
    __shared__ int cnt[128];
    __shared__ int exc[128];
    __shared__ int cur[128];
    if (t < 128) cnt[t] = 0;
    if (t < Nn) mark[b * Nn + t] = 0;
    __syncthreads();
    const int* eis = ei + (size_t)b * 2 * Ee;       // src row
    const int* eid = eis + Ee;                      // dst row
    for (int e = t; e < Ee; e += 256) atomicAdd(&cnt[eid[e]], 1);
    __syncthreads();
    if (t < 128) exc[t] = cnt[t];
    __syncthreads();
    for (int d = 1; d < 128; d <<= 1) {
        int v = 0;
        if (t < 128 && t >= d) v = exc[t - d];
        __syncthreads();
        if (t < 128) exc[t] += v;
        __syncthreads();
    }
    if (t < 128) { int e0 = exc[t] - cnt[t]; exc[t] = e0; cur[t] = e0; }  // exclusive
    __syncthreads();
    if (t < Nn) off[b * Nn + t] = b * Ee + exc[t];
    if (b == Bb - 1 && t == 0) off[NTOT] = ETOT;
    for (int e = t; e < Ee; e += 256) {
        int dst = eid[e];
        int idx = atomicAdd(&cur[dst], 1);
        cpair[b * Ee + idx] = make_int2(eis[e] + b * Nn, b * Ee + e);
    }
    // mark = agent node + srcs of its in-edges (re-read ei: L2-hot)
    int an = agent[b];
    __syncthreads();
    if (t == 0) mark[b * Nn + an] = 1;
    for (int e = t; e < Ee; e += 256) {
        if (eid[e] == an) mark[b * Nn + eis[e]] = 1;
    }
}

// ---------------- K_mlpz: fused edge-MLP + node-sum + q/k/v ----------------
// one wave per node; thread-owns-edge MLP in regs; LDS[64][17] transpose

__device__ __forceinline__ void ln_reg(float* h, const float* __restrict__ g,
                                       const float* __restrict__ b) {
    float s = 0.f;
#pragma unroll
    for (int c = 0; c < 16; c++) s += h[c];
    float m = s * 0.0625f;
    float v = 0.f;
#pragma unroll
    for (int c = 0; c < 16; c++) { float d = h[c] - m; v += d * d; }
    float r = rsqrtf(v * 0.0625f + 1e-5f);
#pragma unroll
    for (int c = 0; c < 16; c++) h[c] = (h[c] - m) * r * g[c] + b[c];
}

__global__ __launch_bounds__(256) void k_mlpz(
    const float* __restrict__ nf, const float* __restrict__ ea, const float* __restrict__ ee,
    const float* __restrict__ W1, const float* __restrict__ b1,
    const float* __restrict__ W2, const float* __restrict__ b2,
    const float* __restrict__ W3, const float* __restrict__ b3,
    const float* __restrict__ lg, const float* __restrict__ lb,
    const float* __restrict__ Wq, const float* __restrict__ bq,
    const float* __restrict__ Wk, const float* __restrict__ bk,
    const float* __restrict__ Wv, const float* __restrict__ bv,
    const int* __restrict__ off, const int2* __restrict__ cpair,
    float* __restrict__ z, float* __restrict__ q1, float* __restrict__ k1, float* __restrict__ v1)
{
    __shared__ float hs[4][64][17];   // stride 17: 2 lanes/bank on write & read = free
    __shared__ int sdeg[4];
    int lane = threadIdx.x & 63;
    int wid  = threadIdx.x >> 6;
    int n    = (blockIdx.x & 7) * (NTOT / 8) + (blockIdx.x >> 3) * 4 + wid;

    int o0 = off[n];
    int deg = off[n + 1] - o0;
    if (lane == 0) sdeg[wid] = deg;
    __syncthreads();
    int mdeg = max(max(sdeg[0], sdeg[1]), max(sdeg[2], sdeg[3]));
    int chunks = (mdeg + 63) >> 6;

    float zp = 0.f;
    for (int ch = 0; ch < chunks; ch++) {
        int i = ch * 64 + lane;
        float h3[16];
        if (i < deg) {
            int2 p = cpair[o0 + i];
            int et = (int)nf[p.x];
            float in[12];
#pragma unroll
            for (int j = 0; j < 4; j++) in[j] = ee[et * 4 + j];
            const float4* ea4 = (const float4*)(ea + (size_t)p.y * 8);
            float4 ua = ea4[0], ub = ea4[1];
            in[4] = ua.x; in[5] = ua.y; in[6] = ua.z; in[7] = ua.w;
            in[8] = ub.x; in[9] = ub.y; in[10] = ub.z; in[11] = ub.w;

            float h1[16];
#pragma unroll
            for (int c = 0; c < 16; c++) {
                float s = b1[c];
#pragma unroll
                for (int j = 0; j < 12; j++) s = fmaf(W1[c * 12 + j], in[j], s);
                h1[c] = fmaxf(s, 0.f);
            }
            ln_reg(h1, lg, lb);
            float h2[16];
#pragma unroll
            for (int c = 0; c < 16; c++) {
                float s = b2[c];
#pragma unroll
                for (int j = 0; j < 16; j++) s = fmaf(W2[c * 16 + j], h1[j], s);
                h2[c] = fmaxf(s, 0.f);
            }
            ln_reg(h2, lg, lb);
#pragma unroll
            for (int c = 0; c < 16; c++) {
                float s = b3[c];
#pragma unroll
                for (int j = 0; j < 16; j++) s = fmaf(W3[c * 16 + j], h2[j], s);
                h3[c] = fmaxf(s, 0.f);
            }
            ln_reg(h3, lg, lb);
        } else {
#pragma unroll
            for (int c = 0; c < 16; c++) h3[c] = 0.f;
        }
#pragma unroll
        for (int c = 0; c < 16; c++) hs[wid][lane][c] = h3[c];
        __syncthreads();
        int g = lane >> 4, c = lane & 15;
        float s = 0.f;
#pragma unroll
        for (int k = 0; k < 16; k++) s += hs[wid][g * 16 + k][c];
        s += __shfl_xor(s, 16);
        s += __shfl_xor(s, 32);
        zp += s;
        __syncthreads();
    }

    if (lane < 16) z[n * 16 + lane] = zp;

    float aq = bq[lane], ak = bk[lane], av = bv[lane];
#pragma unroll
    for (int j = 0; j < 16; j++) {
        float zj = __shfl(zp, j, 16);
        aq = fmaf(Wq[lane * 16 + j], zj, aq);
        ak = fmaf(Wk[lane * 16 + j], zj, ak);
        av = fmaf(Wv[lane * 16 + j], zj, av);
    }
    q1[n * 64 + lane] = aq;
    k1[n * 64 + lane] = ak;
    v1[n * 64 + lane] = av;
}

// ---------------- K_attn1: g1 attention at marked nodes only ----------------

__global__ __launch_bounds__(256) void k_attn1(
    const float* __restrict__ ea,
    const float* __restrict__ q1, const float* __restrict__ k1, const float* __restrict__ v1,
    const float* __restrict__ We, const float* __restrict__ Ws, const float* __restrict__ bs,
    const float* __restrict__ z, const int* __restrict__ mark,
    const int* __restrict__ off, const int2* __restrict__ cpair,
    float* __restrict__ a1)
{
    int lane = threadIdx.x & 63;
    int wid  = threadIdx.x >> 6;
    int n    = (blockIdx.x & 7) * (NTOT / 8) + (blockIdx.x >> 3) * 4 + wid;

    if (!mark[n]) return;   // wave-uniform: a1[n] is never read

    float wer[8];
#pragma unroll
    for (int j = 0; j < 8; j++) wer[j] = We[lane * 8 + j];
    float ql = q1[n * 64 + lane];

    int o0 = off[n];
    int deg = off[n + 1] - o0;

    float m = -1e30f, l = 0.f, acc = 0.f;
    int i = 0;
    for (; i + 2 <= deg; i += 2) {
        int2 pA = cpair[o0 + i];
        int2 pB = cpair[o0 + i + 1];
        const float4* eaA = (const float4*)(ea + (size_t)pA.y * 8);
        const float4* eaB = (const float4*)(ea + (size_t)pB.y * 8);
        float4 a0v = eaA[0], a1v = eaA[1], b0v = eaB[0], b1v = eaB[1];
        float eA = wer[0] * a0v.x + wer[1] * a0v.y + wer[2] * a0v.z + wer[3] * a0v.w
                 + wer[4] * a1v.x + wer[5] * a1v.y + wer[6] * a1v.z + wer[7] * a1v.w;
        float eB = wer[0] * b0v.x + wer[1] * b0v.y + wer[2] * b0v.z + wer[3] * b0v.w
                 + wer[4] * b1v.x + wer[5] * b1v.y + wer[6] * b1v.z + wer[7] * b1v.w;
        float kA = k1[(size_t)pA.x * 64 + lane];
        float kB = k1[(size_t)pB.x * 64 + lane];
        float vA = v1[(size_t)pA.x * 64 + lane];
        float vB = v1[(size_t)pB.x * 64 + lane];
        float tA = ql * (kA + eA);
        float tB = ql * (kB + eB);
        tA += __shfl_xor(tA, 1, 16);  tB += __shfl_xor(tB, 1, 16);
        tA += __shfl_xor(tA, 2, 16);  tB += __shfl_xor(tB, 2, 16);
        tA += __shfl_xor(tA, 4, 16);  tB += __shfl_xor(tB, 4, 16);
        tA += __shfl_xor(tA, 8, 16);  tB += __shfl_xor(tB, 8, 16);
        float lA = tA * 0.25f;
        float lB = tB * 0.25f;
        float nm = fmaxf(m, fmaxf(lA, lB));
        float sc = __expf(m - nm);
        float wA = __expf(lA - nm);
        float wB = __expf(lB - nm);
        acc = acc * sc + wA * (vA + eA) + wB * (vB + eB);
        l   = l * sc + wA + wB;
        m   = nm;
    }
    for (; i < deg; i++) {
        int2 p = cpair[o0 + i];
        const float4* ea4 = (const float4*)(ea + (size_t)p.y * 8);
        float4 u0 = ea4[0], u1 = ea4[1];
        float el = wer[0] * u0.x + wer[1] * u0.y + wer[2] * u0.z + wer[3] * u0.w
                 + wer[4] * u1.x + wer[5] * u1.y + wer[6] * u1.z + wer[7] * u1.w;
        float kl = k1[(size_t)p.x * 64 + lane];
        float t = ql * (kl + el);
        t += __shfl_xor(t, 1, 16);
        t += __shfl_xor(t, 2, 16);
        t += __shfl_xor(t, 4, 16);
        t += __shfl_xor(t, 8, 16);
        float logit = t * 0.25f;
        float nm = fmaxf(m, logit);
        float sc = __expf(m - nm);
        float w  = __expf(logit - nm);
        float vl = v1[(size_t)p.x * 64 + lane];
        acc = acc * sc + w * (vl + el);
        l   = l * sc + w;
        m   = nm;
    }
    float y = (deg > 0) ? (acc / l) : 0.f;
    y += __shfl_xor(y, 16);
    y += __shfl_xor(y, 32);
    y *= 0.25f;

    if (lane < 16) {
        float r = bs[lane];
#pragma unroll
        for (int j = 0; j < 16; j++) r = fmaf(Ws[lane * 16 + j], z[n * 16 + j], r);
        a1[n * 16 + lane] = y + r;
    }
}

// ---------------- K_g2: agent nodes only, 4 waves/batch + LDS merge ----------------

__global__ __launch_bounds__(256) void k_g2(
    const float* __restrict__ ea, const float* __restrict__ a1, const int* __restrict__ agent,
    const float* __restrict__ Wq, const float* __restrict__ bq,
    const float* __restrict__ Wk, const float* __restrict__ bk,
    const float* __restrict__ Wv, const float* __restrict__ bv,
    const float* __restrict__ We, const float* __restrict__ Ws, const float* __restrict__ bs,
    const int* __restrict__ off, const int2* __restrict__ cpair,
    float* __restrict__ out)
{
    __shared__ float sm[4][64], sl[4][64], sa0[4][64], sa1[4][64];
    int b = ((blockIdx.x & 7) << 4) + (blockIdx.x >> 3);
    int lane = threadIdx.x & 63;
    int w = threadIdx.x >> 6;
    int n = b * Nn + agent[b];
    int v0 = lane * 2, v1i = lane * 2 + 1;

    float aa[16];
#pragma unroll
    for (int j = 0; j < 16; j++) aa[j] = a1[n * 16 + j];

    float wk0[16], wk1[16], wv0[16], wv1[16], we0[8], we1[8];
#pragma unroll
    for (int j = 0; j < 16; j++) {
        wk0[j] = Wk[v0 * 16 + j];  wk1[j] = Wk[v1i * 16 + j];
        wv0[j] = Wv[v0 * 16 + j];  wv1[j] = Wv[v1i * 16 + j];
    }
#pragma unroll
    for (int j = 0; j < 8; j++) { we0[j] = We[v0 * 8 + j]; we1[j] = We[v1i * 8 + j]; }

    float q0 = bq[v0], q1v = bq[v1i];
#pragma unroll
    for (int j = 0; j < 16; j++) {
        q0  = fmaf(Wq[v0 * 16 + j],  aa[j], q0);
        q1v = fmaf(Wq[v1i * 16 + j], aa[j], q1v);
    }

    int o0 = off[n];
    int deg = off[n + 1] - o0;

    float m = -1e30f, l = 0.f, a0 = 0.f, a1c = 0.f;
    for (int i = w; i < deg; i += 4) {
        int2 p = cpair[o0 + i];
        int src = p.x, ge = p.y;
        float as[16];
#pragma unroll
        for (int j = 0; j < 16; j++) as[j] = a1[src * 16 + j];
        const float4* ea4 = (const float4*)(ea + (size_t)ge * 8);
        float4 u0 = ea4[0], u1 = ea4[1];
        float eav[8] = {u0.x, u0.y, u0.z, u0.w, u1.x, u1.y, u1.z, u1.w};

        float k0 = bk[v0], k1v = bk[v1i], vv0 = bv[v0], vv1 = bv[v1i];
#pragma unroll
        for (int j = 0; j < 16; j++) {
            k0  = fmaf(wk0[j], as[j], k0);
            k1v = fmaf(wk1[j], as[j], k1v);
            vv0 = fmaf(wv0[j], as[j], vv0);
            vv1 = fmaf(wv1[j], as[j], vv1);
        }
        float e0 = 0.f, e1 = 0.f;
#pragma unroll
        for (int j = 0; j < 8; j++) { e0 = fmaf(we0[j], eav[j], e0); e1 = fmaf(we1[j], eav[j], e1); }

        float t = q0 * (k0 + e0) + q1v * (k1v + e1);
        t += __shfl_xor(t, 1, 16);
        t += __shfl_xor(t, 2, 16);
        t += __shfl_xor(t, 4, 16);
        t += __shfl_xor(t, 8, 16);
        float logit = t * 0.17677669529663687f;  // / sqrt(32)
        float nm = fmaxf(m, logit);
        float sc = __expf(m - nm);
        float wgt = __expf(logit - nm);
        a0  = a0 * sc + wgt * (vv0 + e0);
        a1c = a1c * sc + wgt * (vv1 + e1);
        l   = l * sc + wgt;
        m   = nm;
    }
    sm[w][lane] = m; sl[w][lane] = l; sa0[w][lane] = a0; sa1[w][lane] = a1c;
    __syncthreads();
    if (w == 0) {
        float M = fmaxf(fmaxf(sm[0][lane], sm[1][lane]), fmaxf(sm[2][lane], sm[3][lane]));
        float L = 0.f, A0 = 0.f, A1 = 0.f;
#pragma unroll
        for (int ww = 0; ww < 4; ww++) {
            float sc = __expf(sm[ww][lane] - M);
            L  += sc * sl[ww][lane];
            A0 += sc * sa0[ww][lane];
            A1 += sc * sa1[ww][lane];
        }
        float y0 = (deg > 0) ? (A0 / L) : 0.f;
        float y1 = (deg > 0) ? (A1 / L) : 0.f;
        y0 += __shfl_xor(y0, 16); y0 += __shfl_xor(y0, 32);
        y1 += __shfl_xor(y1, 16); y1 += __shfl_xor(y1, 32);
        y0 *= 0.25f; y1 *= 0.25f;

        if (lane < 16) {
            int c0 = lane * 2, c1 = lane * 2 + 1;
            float r0 = bs[c0], r1 = bs[c1];
#pragma unroll
            for (int j = 0; j < 16; j++) {
                r0 = fmaf(Ws[c0 * 16 + j], aa[j], r0);
                r1 = fmaf(Ws[c1 * 16 + j], aa[j], r1);
            }
            out[b * 32 + c0] = fmaxf(y0 + r0, 0.f);
            out[b * 32 + c1] = fmaxf(y1 + r1, 0.f);
        }
    }
}

// ---------------- launch ----------------

extern "C" void kernel_launch(void* const* d_in, const int* in_sizes, int n_in,
                              void* d_out, int out_size, void* d_ws, size_t ws_size,
                              hipStream_t stream) {
    (void)in_sizes; (void)n_in; (void)out_size; (void)ws_size;
    const float* nf    = (const float*)d_in[0];
    const int*   ei    = (const int*)d_in[1];
    const float* ea    = (const float*)d_in[2];
    const int*   agent = (const int*)d_in[3];
    const float* ee    = (const float*)d_in[4];
    const float* W1    = (const float*)d_in[5];
    const float* b1    = (const float*)d_in[6];
    const float* W2    = (const float*)d_in[7];
    const float* b2    = (const float*)d_in[8];
    const float* W3    = (const float*)d_in[9];
    const float* b3    = (const float*)d_in[10];
    const float* lg    = (const float*)d_in[11];
    const float* lb    = (const float*)d_in[12];
    const float* g1Wq  = (const float*)d_in[13];
    const float* g1bq  = (const float*)d_in[14];
    const float* g1Wk  = (const float*)d_in[15];
    const float* g1bk  = (const float*)d_in[16];
    const float* g1Wv  = (const float*)d_in[17];
    const float* g1bv  = (const float*)d_in[18];
    const float* g1We  = (const float*)d_in[19];
    const float* g1Ws  = (const float*)d_in[20];
    const float* g1bs  = (const float*)d_in[21];
    const float* g2Wq  = (const float*)d_in[22];
    const float* g2bq  = (const float*)d_in[23];
    const float* g2Wk  = (const float*)d_in[24];
    const float* g2bk  = (const float*)d_in[25];
    const float* g2Wv  = (const float*)d_in[26];
    const float* g2bv  = (const float*)d_in[27];
    const float* g2We  = (const float*)d_in[28];
    const float* g2Ws  = (const float*)d_in[29];
    const float* g2bs  = (const float*)d_in[30];
    float* out = (float*)d_out;

    char* w = (char*)d_ws;
    int* mark  = (int*)w;  w += (size_t)NTOT * 4;
    int* off   = (int*)w;  w += (size_t)(NTOT + 4) * 4;
    w = (char*)(((uintptr_t)w + 15) & ~(uintptr_t)15);
    int2* cpair = (int2*)w; w += (size_t)ETOT * 8;
    float* z   = (float*)w; w += (size_t)NTOT * 16 * 4;
    float* q1  = (float*)w; w += (size_t)NTOT * 64 * 4;
    float* k1  = (float*)w; w += (size_t)NTOT * 64 * 4;
    float* v1  = (float*)w; w += (size_t)NTOT * 64 * 4;
    float* a1  = (float*)w; w += (size_t)NTOT * 16 * 4;

    k_csr<<<dim3(Bb), dim3(256), 0, stream>>>(ei, agent, off, cpair, mark);
    k_mlpz<<<dim3(NTOT / 4), dim3(256), 0, stream>>>(
        nf, ea, ee, W1, b1, W2, b2, W3, b3, lg, lb,
        g1Wq, g1bq, g1Wk, g1bk, g1Wv, g1bv,
        off, cpair, z, q1, k1, v1);
    k_attn1<<<dim3(NTOT / 4), dim3(256), 0, stream>>>(
        ea, q1, k1, v1, g1We, g1Ws, g1bs, z, mark, off, cpair, a1);
    k_g2<<<dim3(Bb), dim3(256), 0, stream>>>(
        ea, a1, agent, g2Wq, g2bq, g2Wk, g2bk, g2Wv, g2bv, g2We, g2Ws, g2bs,
        off, cpair, out);
}